// Round 2
// baseline (1407.699 us; speedup 1.0000x reference)
//
#include <hip/hip_runtime.h>
#include <hip/hip_fp16.h>

#define NKr 65536   // N*K
#define LSTR 68     // LDS row stride in halves (136B: 8B-aligned rows, 4-way-max bank conflict)

// ---------------------------------------------------------------------------
// gemv: acc[o] = bias[o] + sum_c w[c*64+o] * row[c]   (w is transposed weight)
// o-loop unrolled (static reg indexing), c-loop rolled (uniform scalar weight
// loads -> s_load; per-thread input from own LDS row).
// ---------------------------------------------------------------------------
__device__ __forceinline__ void gemv64(const __half* __restrict__ row,
                                       const float* __restrict__ w,
                                       const float* __restrict__ bias,
                                       float* __restrict__ acc, bool dorelu)
{
#pragma unroll
    for (int o = 0; o < 64; ++o) acc[o] = bias[o];
#pragma unroll 1
    for (int c0 = 0; c0 < 64; c0 += 4) {
        const __half2 p0 = *(const __half2*)(row + c0);
        const __half2 p1 = *(const __half2*)(row + c0 + 2);
        const float f0 = __low2float(p0), f1 = __high2float(p0);
        const float f2 = __low2float(p1), f3 = __high2float(p1);
        const float* wc = w + (c0 << 6);
#pragma unroll
        for (int o = 0; o < 64; ++o) acc[o] = fmaf(f0, wc[o], acc[o]);
#pragma unroll
        for (int o = 0; o < 64; ++o) acc[o] = fmaf(f1, wc[64 + o], acc[o]);
#pragma unroll
        for (int o = 0; o < 64; ++o) acc[o] = fmaf(f2, wc[128 + o], acc[o]);
#pragma unroll
        for (int o = 0; o < 64; ++o) acc[o] = fmaf(f3, wc[192 + o], acc[o]);
    }
    if (dorelu) {
#pragma unroll
        for (int o = 0; o < 64; ++o) acc[o] = fmaxf(acc[o], 0.0f);
    }
}

__device__ __forceinline__ void store_row(__half* __restrict__ row, const float* __restrict__ acc)
{
#pragma unroll
    for (int o = 0; o < 64; o += 2)
        *(__half2*)(row + o) = __floats2half2_rn(acc[o], acc[o + 1]);
}

// ---------------------------------------------------------------------------
// K0: transpose the 7 64x64 weights (+ 2 64x3) into ws, fp32.
// wt layout (floats): [0..6)*4096 = kWt,vWt,pm2t,pb2t,we1t,we2t,resWt ; pm1t@7*4096 ; pb1t@7*4096+192
// ---------------------------------------------------------------------------
__global__ void k0_kernel(const float* __restrict__ kW, const float* __restrict__ vW,
                          const float* __restrict__ pm2W, const float* __restrict__ pb2W,
                          const float* __restrict__ we1W, const float* __restrict__ we2W,
                          const float* __restrict__ resW,
                          const float* __restrict__ pm1W, const float* __restrict__ pb1W,
                          float* __restrict__ wt)
{
    const int t = threadIdx.x;
    for (int m = 0; m < 7; ++m) {
        const float* src = (m == 0) ? kW : (m == 1) ? vW : (m == 2) ? pm2W : (m == 3) ? pb2W
                         : (m == 4) ? we1W : (m == 5) ? we2W : resW;
        for (int i = t; i < 4096; i += 256)
            wt[m * 4096 + ((i & 63) << 6) + (i >> 6)] = src[i];   // [o][c] -> [c][o]
    }
    for (int i = t; i < 192; i += 256) wt[7 * 4096 + (i % 3) * 64 + (i / 3)] = pm1W[i];
    for (int i = t; i < 192; i += 256) wt[7 * 4096 + 192 + (i % 3) * 64 + (i / 3)] = pb1W[i];
}

// ---------------------------------------------------------------------------
// K1: fused  key/value/pem/peb/rqk/we1/we2  -> writes weight(fp16), val2(fp16)
// one wave per 64 positions; all LDS rows are thread-private (no barriers).
// ---------------------------------------------------------------------------
__global__ void __launch_bounds__(64) k1_kernel(
    const float* __restrict__ xyz, const float* __restrict__ feat,
    const float* __restrict__ wt,
    const float* __restrict__ kb, const float* __restrict__ vb,
    const float* __restrict__ pm1b, const float* __restrict__ pm2b,
    const float* __restrict__ pb1b, const float* __restrict__ pb2b,
    const float* __restrict__ we1b, const float* __restrict__ we2b,
    __half* __restrict__ o_val2, __half* __restrict__ o_wgt)
{
    __shared__ __half bufF[64 * LSTR];
    __shared__ __half bufT[64 * LSTR];
    __shared__ __half bufP[64 * LSTR];
    const int tid = threadIdx.x;
    const int blk = blockIdx.x;
    const int b = blk >> 10;
    const int r = ((blk & 1023) << 6) | tid;
    __half* rowF = bufF + tid * LSTR;
    __half* rowT = bufT + tid * LSTR;
    __half* rowP = bufP + tid * LSTR;

    const float* kWt  = wt;
    const float* vWt  = wt + 4096;
    const float* pm2t = wt + 2 * 4096;
    const float* pb2t = wt + 3 * 4096;
    const float* we1t = wt + 4 * 4096;
    const float* we2t = wt + 5 * 4096;
    const float* pm1t = wt + 7 * 4096;
    const float* pb1t = wt + 7 * 4096 + 192;

    // 1. feature -> bufF (coalesced dword loads, one per channel)
    const float* fb = feat + (size_t)(b * 64) * NKr + r;
#pragma unroll 1
    for (int c = 0; c < 64; c += 2) {
        float a  = fb[(size_t)c * NKr];
        float b2 = fb[(size_t)(c + 1) * NKr];
        *(__half2*)(rowF + c) = __floats2half2_rn(a, b2);
    }
    // 2. xyz
    const float* xb = xyz + (size_t)(b * 3) * NKr + r;
    const float px = xb[0], py = xb[NKr], pz = xb[2 * NKr];

    float acc[64];
    // 3. t2 = relu(pb1 @ xyz + pb1b) -> bufT
#pragma unroll
    for (int o = 0; o < 64; ++o)
        acc[o] = fmaxf(fmaf(px, pb1t[o], fmaf(py, pb1t[64 + o], fmaf(pz, pb1t[128 + o], pb1b[o]))), 0.0f);
    store_row(rowT, acc);
    // 4. peb = pb2 @ t2 + pb2b -> bufP
    gemv64(rowT, pb2t, pb2b, acc, false);
    store_row(rowP, acc);
    // 5. t1 = relu(pm1 @ xyz + pm1b) -> bufT
#pragma unroll
    for (int o = 0; o < 64; ++o)
        acc[o] = fmaxf(fmaf(px, pm1t[o], fmaf(py, pm1t[64 + o], fmaf(pz, pm1t[128 + o], pm1b[o]))), 0.0f);
    store_row(rowT, acc);
    // 6. pem = pm2 @ t1 + pm2b -> bufT (overwrite, t1 dead)
    gemv64(rowT, pm2t, pm2b, acc, false);
    store_row(rowT, acc);
    // 7. key = kW @ f + kb  (stays in acc)
    gemv64(rowF, kWt, kb, acc, false);
    // 8. rqk = key*pem + peb -> bufT (read-then-overwrite, same thread, safe)
#pragma unroll
    for (int o = 0; o < 64; o += 2) {
        const __half2 pm = *(const __half2*)(rowT + o);
        const __half2 pb = *(const __half2*)(rowP + o);
        const float r0 = fmaf(acc[o],     __low2float(pm),  __low2float(pb));
        const float r1 = fmaf(acc[o + 1], __high2float(pm), __high2float(pb));
        *(__half2*)(rowT + o) = __floats2half2_rn(r0, r1);
    }
    // 9. value = vW @ f + vb ; val2 = value + peb -> global (fp16)
    gemv64(rowF, vWt, vb, acc, false);
    {
        __half* vp = o_val2 + (size_t)(b * 64) * NKr + r;
#pragma unroll 1
        for (int o = 0; o < 64; o += 2) {
            const __half2 pb = *(const __half2*)(rowP + o);
            vp[(size_t)o * NKr]       = __float2half(acc[o] + __low2float(pb));
            vp[(size_t)(o + 1) * NKr] = __float2half(acc[o + 1] + __high2float(pb));
        }
    }
    // 10. t3 = relu(we1 @ rqk + we1b) -> bufF (f dead)
    gemv64(rowT, we1t, we1b, acc, true);
    store_row(rowF, acc);
    // 11. weight = we2 @ t3 + we2b -> global (fp16)
    gemv64(rowF, we2t, we2b, acc, false);
    {
        __half* wp = o_wgt + (size_t)(b * 64) * NKr + r;
#pragma unroll 1
        for (int o = 0; o < 64; ++o) wp[(size_t)o * NKr] = __float2half(acc[o]);
    }
}

// ---------------------------------------------------------------------------
// K2: per (b,c): max & sum(exp) over n for each of the 16 k's. Coalesced 16B
// chunks; chunk parity = k-half. Writes m and 1/sum.
// ---------------------------------------------------------------------------
__device__ __forceinline__ void dec8(const uint4 u, float v[8])
{
    v[0] = __half2float(__ushort_as_half((unsigned short)(u.x & 0xffffu)));
    v[1] = __half2float(__ushort_as_half((unsigned short)(u.x >> 16)));
    v[2] = __half2float(__ushort_as_half((unsigned short)(u.y & 0xffffu)));
    v[3] = __half2float(__ushort_as_half((unsigned short)(u.y >> 16)));
    v[4] = __half2float(__ushort_as_half((unsigned short)(u.z & 0xffffu)));
    v[5] = __half2float(__ushort_as_half((unsigned short)(u.z >> 16)));
    v[6] = __half2float(__ushort_as_half((unsigned short)(u.w & 0xffffu)));
    v[7] = __half2float(__ushort_as_half((unsigned short)(u.w >> 16)));
}

__global__ void __launch_bounds__(256) k2_kernel(const __half* __restrict__ wgt,
                                                 float* __restrict__ mv, float* __restrict__ rs)
{
    __shared__ float red[4][2][8];
    __shared__ float msh[16];
    const int bc = blockIdx.x;                 // b*64 + c
    const __half* base = wgt + (size_t)bc * NKr;
    const int t = threadIdx.x;
    const int par = t & 1;                     // k-half of all my chunks
    const int wave = t >> 6, lane = t & 63;

    float mx[8];
#pragma unroll
    for (int j = 0; j < 8; ++j) mx[j] = -3.0e38f;
#pragma unroll 1
    for (int i = 0; i < 32; ++i) {
        const uint4 u = *(const uint4*)(base + ((size_t)(t + (i << 8)) << 3));
        float v[8]; dec8(u, v);
#pragma unroll
        for (int j = 0; j < 8; ++j) mx[j] = fmaxf(mx[j], v[j]);
    }
#pragma unroll
    for (int m2 = 2; m2 <= 32; m2 <<= 1) {
#pragma unroll
        for (int j = 0; j < 8; ++j) mx[j] = fmaxf(mx[j], __shfl_xor(mx[j], m2, 64));
    }
    if (lane < 2) {
#pragma unroll
        for (int j = 0; j < 8; ++j) red[wave][lane][j] = mx[j];
    }
    __syncthreads();
    if (t < 16) {
        const int p = t >> 3, j = t & 7;
        msh[t] = fmaxf(fmaxf(red[0][p][j], red[1][p][j]), fmaxf(red[2][p][j], red[3][p][j]));
    }
    __syncthreads();
    float mk[8];
#pragma unroll
    for (int j = 0; j < 8; ++j) mk[j] = msh[par * 8 + j];
    float sm[8] = {0, 0, 0, 0, 0, 0, 0, 0};
#pragma unroll 1
    for (int i = 0; i < 32; ++i) {
        const uint4 u = *(const uint4*)(base + ((size_t)(t + (i << 8)) << 3));
        float v[8]; dec8(u, v);
#pragma unroll
        for (int j = 0; j < 8; ++j) sm[j] += exp2f((v[j] - mk[j]) * 1.44269504f);
    }
#pragma unroll
    for (int m2 = 2; m2 <= 32; m2 <<= 1) {
#pragma unroll
        for (int j = 0; j < 8; ++j) sm[j] += __shfl_xor(sm[j], m2, 64);
    }
    if (lane < 2) {
#pragma unroll
        for (int j = 0; j < 8; ++j) red[wave][lane][j] = sm[j];
    }
    __syncthreads();
    if (t < 16) {
        const int p = t >> 3, j = t & 7;
        const float s = red[0][p][j] + red[1][p][j] + red[2][p][j] + red[3][p][j];
        mv[bc * 16 + t] = msh[t];
        rs[bc * 16 + t] = 1.0f / s;
    }
}

// ---------------------------------------------------------------------------
// K3: score = exp(w-m)*rs ; feature = relu(score*val2) ; out = resW@feature + resb
// ---------------------------------------------------------------------------
__global__ void __launch_bounds__(64) k3_kernel(
    const __half* __restrict__ wgt, const __half* __restrict__ val2,
    const float* __restrict__ mv, const float* __restrict__ rs,
    const float* __restrict__ wt, const float* __restrict__ resb,
    float* __restrict__ out)
{
    __shared__ __half bufF[64 * LSTR];
    __shared__ float mloc[1024];
    __shared__ float rloc[1024];
    const int tid = threadIdx.x;
    const int blk = blockIdx.x;
    const int b = blk >> 10;
    const int r = ((blk & 1023) << 6) | tid;
    __half* rowF = bufF + tid * LSTR;

    {   // stage this batch's softmax stats (64c x 16k)
        const float* ms = mv + b * 1024;
        const float* rp = rs + b * 1024;
#pragma unroll
        for (int i = 0; i < 16; ++i) {
            mloc[tid + 64 * i] = ms[tid + 64 * i];
            rloc[tid + 64 * i] = rp[tid + 64 * i];
        }
    }
    __syncthreads();

    const __half* wp = wgt + (size_t)(b * 64) * NKr + r;
    const __half* vp = val2 + (size_t)(b * 64) * NKr + r;
    const int kk = tid & 15;
#pragma unroll 1
    for (int c = 0; c < 64; c += 2) {
        const float w0 = __half2float(wp[(size_t)c * NKr]);
        const float w1 = __half2float(wp[(size_t)(c + 1) * NKr]);
        const float v0 = __half2float(vp[(size_t)c * NKr]);
        const float v1 = __half2float(vp[(size_t)(c + 1) * NKr]);
        const float s0 = exp2f((w0 - mloc[c * 16 + kk]) * 1.44269504f) * rloc[c * 16 + kk];
        const float s1 = exp2f((w1 - mloc[(c + 1) * 16 + kk]) * 1.44269504f) * rloc[(c + 1) * 16 + kk];
        const float f0 = fmaxf(s0 * v0, 0.0f);
        const float f1 = fmaxf(s1 * v1, 0.0f);
        *(__half2*)(rowF + c) = __floats2half2_rn(f0, f1);
    }
    float acc[64];
    gemv64(rowF, wt + 6 * 4096, resb, acc, false);   // resWt
    float* op = out + (size_t)(b * 64) * NKr + r;
#pragma unroll 1
    for (int o = 0; o < 64; ++o) op[(size_t)o * NKr] = acc[o];
}

// ---------------------------------------------------------------------------
extern "C" void kernel_launch(void* const* d_in, const int* in_sizes, int n_in,
                              void* d_out, int out_size, void* d_ws, size_t ws_size,
                              hipStream_t stream)
{
    const float* xyz  = (const float*)d_in[0];
    const float* feat = (const float*)d_in[1];
    const float* kW   = (const float*)d_in[2];  const float* kb   = (const float*)d_in[3];
    const float* vW   = (const float*)d_in[4];  const float* vb   = (const float*)d_in[5];
    const float* pm1W = (const float*)d_in[6];  const float* pm1b = (const float*)d_in[7];
    const float* pm2W = (const float*)d_in[8];  const float* pm2b = (const float*)d_in[9];
    const float* pb1W = (const float*)d_in[10]; const float* pb1b = (const float*)d_in[11];
    const float* pb2W = (const float*)d_in[12]; const float* pb2b = (const float*)d_in[13];
    const float* we1W = (const float*)d_in[14]; const float* we1b = (const float*)d_in[15];
    const float* we2W = (const float*)d_in[16]; const float* we2b = (const float*)d_in[17];
    const float* resW = (const float*)d_in[18]; const float* resb = (const float*)d_in[19];

    float*  wt   = (float*)d_ws;                       // 29056 floats used
    float*  mv   = wt + 32768;                         // 8192 floats
    float*  rsum = wt + 40960;                         // 8192 floats
    __half* val2 = (__half*)((char*)d_ws + 196608);            // 33.5M halves
    __half* wgt  = (__half*)((char*)d_ws + 196608 + 67108864); // 33.5M halves

    k0_kernel<<<1, 256, 0, stream>>>(kW, vW, pm2W, pb2W, we1W, we2W, resW, pm1W, pb1W, wt);
    k1_kernel<<<8192, 64, 0, stream>>>(xyz, feat, wt, kb, vb, pm1b, pm2b, pb1b, pb2b,
                                       we1b, we2b, val2, wgt);
    k2_kernel<<<512, 256, 0, stream>>>(wgt, mv, rsum);
    k3_kernel<<<8192, 64, 0, stream>>>(wgt, val2, mv, rsum, wt, resb, (float*)d_out);
}

// Round 3
// 488.951 us; speedup vs baseline: 2.8790x; 2.8790x over previous
//
#include <hip/hip_runtime.h>
#include <hip/hip_fp16.h>

#define NKr 65536   // N*K positions per batch
#define LOG2E 1.44269504f

typedef __attribute__((ext_vector_type(4))) float f32x4;
typedef __attribute__((ext_vector_type(8))) short s16x8;

// fp32 -> bf16 (RNE)
__device__ __forceinline__ short bfc(float x){
    union{float f; unsigned u;} a; a.f = x;
    unsigned r = a.u + 0x7fffu + ((a.u >> 16) & 1u);
    return (short)(r >> 16);
}
__device__ __forceinline__ short hfc(float x){
    __half h = __float2half(x);
    return *(short*)&h;
}
__device__ __forceinline__ float hdec(unsigned short s){
    __half h = *(__half*)&s;
    return __half2float(h);
}

// ---------------------------------------------------------------------------
// K0: convert weights to bf16 (no transpose: A-operand wants W[o][c] rows).
// wbf layout (halves): pm1p@0 [64][32] zero-padded, pb1p@2048 [64][32],
// then 64x64 mats: pm2@4096, pb2@8192, kW@12288, vW@16384, we1@20480,
// we2@24576, resW@28672.
// ---------------------------------------------------------------------------
__global__ void k0_kernel(const float* __restrict__ pm1W, const float* __restrict__ pb1W,
                          const float* __restrict__ pm2W, const float* __restrict__ pb2W,
                          const float* __restrict__ kW,   const float* __restrict__ vW,
                          const float* __restrict__ we1W, const float* __restrict__ we2W,
                          const float* __restrict__ resW, short* __restrict__ wbf)
{
    const int t = threadIdx.x;
    for (int i = t; i < 2048; i += 256){
        int o = i >> 5, c = i & 31;
        wbf[i]        = (c < 3) ? bfc(pm1W[o*3 + c]) : (short)0;
        wbf[2048 + i] = (c < 3) ? bfc(pb1W[o*3 + c]) : (short)0;
    }
    const float* srcs[7] = {pm2W, pb2W, kW, vW, we1W, we2W, resW};
    for (int m = 0; m < 7; ++m){
        const float* s = srcs[m];
        for (int i = t; i < 4096; i += 256) wbf[4096 + m*4096 + i] = bfc(s[i]);
    }
}

// ---------------------------------------------------------------------------
// MFMA helpers. Tile layout: position-major [p][64c] bf16/fp16, 128B rows,
// XOR-swizzled: half_idx = (p*64 + c) ^ ((p&7)<<3)  (16B-granule swizzle).
// MFMA mapping (16x16x32 bf16): A lane: m=li, k=hi*8+j ; B lane: k=hi*8+j,
// n=li ; D lane: row=o=16mi+4hi+j, col=p=16ni+li  (li=l&15, hi=l>>4).
// A = weight rows W[o][c] straight from wbf; B = activation frags from LDS.
// ---------------------------------------------------------------------------
__device__ __forceinline__ void gemm64(const short* __restrict__ S,
                                       const short* __restrict__ wbf, int wo,
                                       const float* __restrict__ bias,
                                       int li, int hi, f32x4 acc[4][4])
{
#pragma unroll
    for (int mi = 0; mi < 4; ++mi){
        const float4 bv = *(const float4*)(bias + 16*mi + 4*hi);
#pragma unroll
        for (int ni = 0; ni < 4; ++ni){
            acc[mi][ni][0] = bv.x; acc[mi][ni][1] = bv.y;
            acc[mi][ni][2] = bv.z; acc[mi][ni][3] = bv.w;
        }
    }
#pragma unroll
    for (int ks = 0; ks < 2; ++ks){
        s16x8 af[4];
#pragma unroll
        for (int mi = 0; mi < 4; ++mi)
            af[mi] = *(const s16x8*)(wbf + wo + (16*mi + li)*64 + ks*32 + hi*8);
#pragma unroll
        for (int ni = 0; ni < 4; ++ni){
            const int p = 16*ni + li;
            const s16x8 bf_ = *(const s16x8*)(S + ((p*64 + ks*32 + hi*8) ^ ((li & 7) << 3)));
#pragma unroll
            for (int mi = 0; mi < 4; ++mi)
                acc[mi][ni] = __builtin_amdgcn_mfma_f32_16x16x32_bf16(af[mi], bf_, acc[mi][ni], 0, 0, 0);
        }
    }
}

// K=32 GEMM with B-frags in registers (xyz, padded K 3->32)
__device__ __forceinline__ void gemm32x(const s16x8* __restrict__ xf,
                                        const short* __restrict__ wbf, int wo,
                                        const float* __restrict__ bias,
                                        int li, int hi, f32x4 acc[4][4])
{
#pragma unroll
    for (int mi = 0; mi < 4; ++mi){
        const float4 bv = *(const float4*)(bias + 16*mi + 4*hi);
#pragma unroll
        for (int ni = 0; ni < 4; ++ni){
            acc[mi][ni][0] = bv.x; acc[mi][ni][1] = bv.y;
            acc[mi][ni][2] = bv.z; acc[mi][ni][3] = bv.w;
        }
    }
    s16x8 af[4];
#pragma unroll
    for (int mi = 0; mi < 4; ++mi)
        af[mi] = *(const s16x8*)(wbf + wo + (16*mi + li)*32 + hi*8);
#pragma unroll
    for (int ni = 0; ni < 4; ++ni)
#pragma unroll
        for (int mi = 0; mi < 4; ++mi)
            acc[mi][ni] = __builtin_amdgcn_mfma_f32_16x16x32_bf16(af[mi], xf[ni], acc[mi][ni], 0, 0, 0);
}

// D-frags -> swizzled LDS tile, bf16 (optional relu)
__device__ __forceinline__ void dstore_bf(short* __restrict__ Tt, f32x4 acc[4][4],
                                          int li, int hi, bool relu)
{
#pragma unroll
    for (int mi = 0; mi < 4; ++mi){
        const int o0 = 16*mi + 4*hi;
#pragma unroll
        for (int ni = 0; ni < 4; ++ni){
            const int p = 16*ni + li;
            float a0 = acc[mi][ni][0], a1 = acc[mi][ni][1];
            float a2 = acc[mi][ni][2], a3 = acc[mi][ni][3];
            if (relu){ a0 = fmaxf(a0, 0.f); a1 = fmaxf(a1, 0.f);
                       a2 = fmaxf(a2, 0.f); a3 = fmaxf(a3, 0.f); }
            uint2 pk;
            pk.x = (unsigned)(unsigned short)bfc(a0) | ((unsigned)(unsigned short)bfc(a1) << 16);
            pk.y = (unsigned)(unsigned short)bfc(a2) | ((unsigned)(unsigned short)bfc(a3) << 16);
            *(uint2*)(Tt + ((p*64 + o0) ^ ((li & 7) << 3))) = pk;
        }
    }
}

// D-frags -> swizzled LDS tile, fp16
__device__ __forceinline__ void dstore_h16(short* __restrict__ Tt, f32x4 acc[4][4],
                                           int li, int hi)
{
#pragma unroll
    for (int mi = 0; mi < 4; ++mi){
        const int o0 = 16*mi + 4*hi;
#pragma unroll
        for (int ni = 0; ni < 4; ++ni){
            const int p = 16*ni + li;
            uint2 pk;
            pk.x = (unsigned)(unsigned short)hfc(acc[mi][ni][0]) | ((unsigned)(unsigned short)hfc(acc[mi][ni][1]) << 16);
            pk.y = (unsigned)(unsigned short)hfc(acc[mi][ni][2]) | ((unsigned)(unsigned short)hfc(acc[mi][ni][3]) << 16);
            *(uint2*)(Tt + ((p*64 + o0) ^ ((li & 7) << 3))) = pk;
        }
    }
}

// swizzled tile row l -> global (coalesced dwordx4 per 16B)
__device__ __forceinline__ void tstore(const short* __restrict__ Tt, short* __restrict__ gout, int l)
{
#pragma unroll
    for (int g = 0; g < 8; ++g){
        uint4 d = *(const uint4*)(Tt + ((l*64 + g*8) ^ ((l & 7) << 3)));
        *(uint4*)(gout + g*8) = d;
    }
}

// ---------------------------------------------------------------------------
// K1: full fused MFMA chain -> wgt (fp16, [b][r][c]) , val2 (fp16, [b][r][c])
// One wave = 64 positions. 4 waves/block, wave-private LDS, zero barriers.
// ---------------------------------------------------------------------------
__global__ void __launch_bounds__(256, 2) k1_kernel(
    const float* __restrict__ xyz, const float* __restrict__ feat,
    const short* __restrict__ wbf,
    const float* __restrict__ kb,  const float* __restrict__ vb,
    const float* __restrict__ pm1b, const float* __restrict__ pm2b,
    const float* __restrict__ pb1b, const float* __restrict__ pb2b,
    const float* __restrict__ we1b, const float* __restrict__ we2b,
    short* __restrict__ o_val2, short* __restrict__ o_wgt)
{
    __shared__ short lds[8][4096];   // [0..3]=F tiles, [4..7]=T tiles (8KB each)
    const int tid = threadIdx.x;
    const int w = tid >> 6, l = tid & 63;
    const int li = l & 15, hi = l >> 4;
    short* F = lds[w];
    short* T = lds[4 + w];
    const int b = blockIdx.x >> 8;
    const int rbase = (blockIdx.x & 255) * 256 + w * 64;

    // ---- stage feature tile: [p=l][c] bf16, swizzled ----
    {
        const float* fb = feat + (size_t)(b * 64) * NKr + rbase + l;
#pragma unroll 2
        for (int c0 = 0; c0 < 64; c0 += 8){
            short v[8];
#pragma unroll
            for (int j = 0; j < 8; ++j) v[j] = bfc(fb[(size_t)(c0 + j) * NKr]);
            uint4 pk;
            pk.x = (unsigned)(unsigned short)v[0] | ((unsigned)(unsigned short)v[1] << 16);
            pk.y = (unsigned)(unsigned short)v[2] | ((unsigned)(unsigned short)v[3] << 16);
            pk.z = (unsigned)(unsigned short)v[4] | ((unsigned)(unsigned short)v[5] << 16);
            pk.w = (unsigned)(unsigned short)v[6] | ((unsigned)(unsigned short)v[7] << 16);
            *(uint4*)(F + ((l*64 + c0) ^ ((l & 7) << 3))) = pk;
        }
    }
    // ---- xyz B-frags in regs (K padded 3->32; only hi==0 lanes non-zero) ----
    s16x8 xf[4];
#pragma unroll
    for (int ni = 0; ni < 4; ++ni)
#pragma unroll
        for (int j = 0; j < 8; ++j) xf[ni][j] = 0;
    if (hi == 0){
        const float* xb = xyz + (size_t)(b * 3) * NKr + rbase;
#pragma unroll
        for (int ni = 0; ni < 4; ++ni){
            const int p = 16*ni + li;
            xf[ni][0] = bfc(xb[p]);
            xf[ni][1] = bfc(xb[NKr + p]);
            xf[ni][2] = bfc(xb[2*NKr + p]);
        }
    }

    f32x4 A1[4][4], A2[4][4];
    // key = kW@f + kb
    gemm64(F, wbf, 12288, kb, li, hi, A1);
    // t1 = relu(pm1@xyz + pm1b) -> T
    gemm32x(xf, wbf, 0, pm1b, li, hi, A2);
    dstore_bf(T, A2, li, hi, true);
    // pem = pm2@t1 + pm2b
    gemm64(T, wbf, 4096, pm2b, li, hi, A2);
    // kp = key * pem
#pragma unroll
    for (int mi = 0; mi < 4; ++mi)
#pragma unroll
        for (int ni = 0; ni < 4; ++ni)
#pragma unroll
            for (int j = 0; j < 4; ++j) A1[mi][ni][j] *= A2[mi][ni][j];
    // t2 = relu(pb1@xyz + pb1b) -> T
    gemm32x(xf, wbf, 2048, pb1b, li, hi, A2);
    dstore_bf(T, A2, li, hi, true);
    // peb = pb2@t2 + pb2b   (stays live in A2)
    gemm64(T, wbf, 8192, pb2b, li, hi, A2);
    // rqk = kp + peb -> T
#pragma unroll
    for (int mi = 0; mi < 4; ++mi)
#pragma unroll
        for (int ni = 0; ni < 4; ++ni)
#pragma unroll
            for (int j = 0; j < 4; ++j) A1[mi][ni][j] += A2[mi][ni][j];
    dstore_bf(T, A1, li, hi, false);
    // value = vW@f + vb ; val2 = value + peb -> F (fp16) -> global
    gemm64(F, wbf, 16384, vb, li, hi, A1);
#pragma unroll
    for (int mi = 0; mi < 4; ++mi)
#pragma unroll
        for (int ni = 0; ni < 4; ++ni)
#pragma unroll
            for (int j = 0; j < 4; ++j) A1[mi][ni][j] += A2[mi][ni][j];
    dstore_h16(F, A1, li, hi);
    const size_t rowoff = ((size_t)b * NKr + rbase + l) * 64;
    tstore(F, o_val2 + rowoff, l);
    // t3 = relu(we1@rqk + we1b) -> F
    gemm64(T, wbf, 20480, we1b, li, hi, A1);
    dstore_bf(F, A1, li, hi, true);
    // wgt = we2@t3 + we2b -> T (fp16) -> global
    gemm64(F, wbf, 24576, we2b, li, hi, A1);
    dstore_h16(T, A1, li, hi);
    tstore(T, o_wgt + rowoff, l);
}

// ---------------------------------------------------------------------------
// K2: online softmax stats over n per (b,c,k). wgt is [b][n*16+k][c] fp16.
// grid = b(8) x k(16) x chalf(2) = 256 blocks, 256 thr. One pass, no scratch.
// ---------------------------------------------------------------------------
__device__ __forceinline__ void comb(float& m, float& S, float mo, float So)
{
    float mn = fmaxf(m, mo);
    S = S * exp2f((m - mn) * LOG2E) + So * exp2f((mo - mn) * LOG2E);
    m = mn;
}

__global__ void __launch_bounds__(256) k2_kernel(const short* __restrict__ wgt,
                                                 float* __restrict__ mstat,
                                                 float* __restrict__ rstat)
{
    __shared__ float redm[4][4][8], reds[4][4][8];
    const int blk = blockIdx.x;
    const int b = blk >> 5, k = (blk >> 1) & 15, h = blk & 1;
    const int t = threadIdx.x;
    const int oct = t & 3, g = t >> 2;            // c0 = h*32+oct*8 ; row group g
    const short* wp = wgt + (size_t)b * NKr * 64 + (size_t)k * 64 + h * 32 + oct * 8;

    float m[8], S[8];
#pragma unroll
    for (int j = 0; j < 8; ++j){ m[j] = -3.0e38f; S[j] = 0.f; }
#pragma unroll 1
    for (int i = 0; i < 64; ++i){
        const int n = g + 64 * i;
        const uint4 u = *(const uint4*)(wp + (size_t)n * 1024);
        unsigned short hs[8] = {
            (unsigned short)(u.x & 0xffffu), (unsigned short)(u.x >> 16),
            (unsigned short)(u.y & 0xffffu), (unsigned short)(u.y >> 16),
            (unsigned short)(u.z & 0xffffu), (unsigned short)(u.z >> 16),
            (unsigned short)(u.w & 0xffffu), (unsigned short)(u.w >> 16)};
#pragma unroll
        for (int j = 0; j < 8; ++j){
            const float x = hdec(hs[j]);
            const float mn = fmaxf(m[j], x);
            S[j] = S[j] * exp2f((m[j] - mn) * LOG2E) + exp2f((x - mn) * LOG2E);
            m[j] = mn;
        }
    }
    // in-wave reduce across g (threads sharing oct: xor 4,8,16,32)
#pragma unroll
    for (int d = 4; d <= 32; d <<= 1){
#pragma unroll
        for (int j = 0; j < 8; ++j){
            float mo = __shfl_xor(m[j], d, 64);
            float So = __shfl_xor(S[j], d, 64);
            comb(m[j], S[j], mo, So);
        }
    }
    const int wv = t >> 6, ln = t & 63;
    if (ln < 4){
#pragma unroll
        for (int j = 0; j < 8; ++j){ redm[wv][ln][j] = m[j]; reds[wv][ln][j] = S[j]; }
    }
    __syncthreads();
    if (t < 32){
        const int oc = t >> 3, j = t & 7;
        float M = redm[0][oc][j], Sm = reds[0][oc][j];
#pragma unroll
        for (int wv2 = 1; wv2 < 4; ++wv2) comb(M, Sm, redm[wv2][oc][j], reds[wv2][oc][j]);
        const int idx = (b * 16 + k) * 64 + h * 32 + oc * 8 + j;
        mstat[idx] = M;
        rstat[idx] = 1.0f / Sm;
    }
}

// ---------------------------------------------------------------------------
// K3: score = exp(w-m)*rs ; feature = relu(score*val2) -> MFMA resW -> out
// ---------------------------------------------------------------------------
__global__ void __launch_bounds__(256, 3) k3_kernel(
    const short* __restrict__ wgt, const short* __restrict__ val2,
    const float* __restrict__ mstat, const float* __restrict__ rstat,
    const short* __restrict__ wbf, const float* __restrict__ resb,
    float* __restrict__ out)
{
    __shared__ short ftile[4][4096];
    __shared__ float mls[1024], rls[1024];      // [k][c] fp32, swizzled f^=((k&7)<<2)
    const int tid = threadIdx.x;
    const int w = tid >> 6, l = tid & 63;
    const int li = l & 15, hi = l >> 4;
    const int b = blockIdx.x >> 8;
    const int rblk = (blockIdx.x & 255) * 256;
    const int rbase = rblk + w * 64;

    {
        const float* mp = mstat + b * 1024;
        const float* rp = rstat + b * 1024;
#pragma unroll
        for (int i = 0; i < 4; ++i){
            const int f = tid + 256 * i;
            const int kk = f >> 6;
            const int fs = f ^ ((kk & 7) << 2);
            mls[fs] = mp[f];
            rls[fs] = rp[f];
        }
    }
    __syncthreads();

    short* Ft = ftile[w];
    const int k = l & 15;                        // rbase % 16 == 0
    const size_t rowoff = ((size_t)b * NKr + rbase + l) * 64;
    const short* wp = wgt + rowoff;
    const short* vp = val2 + rowoff;
#pragma unroll 2
    for (int g = 0; g < 8; ++g){
        const uint4 uw = *(const uint4*)(wp + g * 8);
        const uint4 uv = *(const uint4*)(vp + g * 8);
        const int f0 = (k * 64 + g * 8) ^ ((k & 7) << 2);
        const int f1 = (k * 64 + g * 8 + 4) ^ ((k & 7) << 2);
        const float4 m0 = *(const float4*)(mls + f0);
        const float4 m1 = *(const float4*)(mls + f1);
        const float4 r0 = *(const float4*)(rls + f0);
        const float4 r1 = *(const float4*)(rls + f1);
        const unsigned short ws8[8] = {
            (unsigned short)(uw.x & 0xffffu), (unsigned short)(uw.x >> 16),
            (unsigned short)(uw.y & 0xffffu), (unsigned short)(uw.y >> 16),
            (unsigned short)(uw.z & 0xffffu), (unsigned short)(uw.z >> 16),
            (unsigned short)(uw.w & 0xffffu), (unsigned short)(uw.w >> 16)};
        const unsigned short vs8[8] = {
            (unsigned short)(uv.x & 0xffffu), (unsigned short)(uv.x >> 16),
            (unsigned short)(uv.y & 0xffffu), (unsigned short)(uv.y >> 16),
            (unsigned short)(uv.z & 0xffffu), (unsigned short)(uv.z >> 16),
            (unsigned short)(uv.w & 0xffffu), (unsigned short)(uv.w >> 16)};
        const float mv[8] = {m0.x, m0.y, m0.z, m0.w, m1.x, m1.y, m1.z, m1.w};
        const float rv[8] = {r0.x, r0.y, r0.z, r0.w, r1.x, r1.y, r1.z, r1.w};
        short fo[8];
#pragma unroll
        for (int j = 0; j < 8; ++j){
            const float sc = exp2f((hdec(ws8[j]) - mv[j]) * LOG2E) * rv[j];
            fo[j] = bfc(fmaxf(sc * hdec(vs8[j]), 0.f));
        }
        uint4 pk;
        pk.x = (unsigned)(unsigned short)fo[0] | ((unsigned)(unsigned short)fo[1] << 16);
        pk.y = (unsigned)(unsigned short)fo[2] | ((unsigned)(unsigned short)fo[3] << 16);
        pk.z = (unsigned)(unsigned short)fo[4] | ((unsigned)(unsigned short)fo[5] << 16);
        pk.w = (unsigned)(unsigned short)fo[6] | ((unsigned)(unsigned short)fo[7] << 16);
        *(uint4*)(Ft + ((l * 64 + g * 8) ^ ((l & 7) << 3))) = pk;
    }
    // out = resW @ feature + resb
    f32x4 acc[4][4];
    gemm64(Ft, wbf, 28672, resb, li, hi, acc);
    float* op = out + (size_t)b * 64 * NKr;
#pragma unroll
    for (int mi = 0; mi < 4; ++mi){
        const int o0 = 16 * mi + 4 * hi;
#pragma unroll
        for (int ni = 0; ni < 4; ++ni){
            const int r = rbase + 16 * ni + li;
#pragma unroll
            for (int j = 0; j < 4; ++j)
                op[(size_t)(o0 + j) * NKr + r] = acc[mi][ni][j];
        }
    }
}

// ---------------------------------------------------------------------------
extern "C" void kernel_launch(void* const* d_in, const int* in_sizes, int n_in,
                              void* d_out, int out_size, void* d_ws, size_t ws_size,
                              hipStream_t stream)
{
    const float* xyz  = (const float*)d_in[0];
    const float* feat = (const float*)d_in[1];
    const float* kW   = (const float*)d_in[2];  const float* kb   = (const float*)d_in[3];
    const float* vW   = (const float*)d_in[4];  const float* vb   = (const float*)d_in[5];
    const float* pm1W = (const float*)d_in[6];  const float* pm1b = (const float*)d_in[7];
    const float* pm2W = (const float*)d_in[8];  const float* pm2b = (const float*)d_in[9];
    const float* pb1W = (const float*)d_in[10]; const float* pb1b = (const float*)d_in[11];
    const float* pb2W = (const float*)d_in[12]; const float* pb2b = (const float*)d_in[13];
    const float* we1W = (const float*)d_in[14]; const float* we1b = (const float*)d_in[15];
    const float* we2W = (const float*)d_in[16]; const float* we2b = (const float*)d_in[17];
    const float* resW = (const float*)d_in[18]; const float* resb = (const float*)d_in[19];

    short* wbf   = (short*)d_ws;                              // 65536 B
    float* mstat = (float*)((char*)d_ws + 65536);             // 32768 B
    float* rstat = (float*)((char*)d_ws + 98304);             // 32768 B
    short* val2  = (short*)((char*)d_ws + 131072);            // 64 MB
    short* wgt   = (short*)((char*)d_ws + 131072 + 67108864); // 64 MB

    k0_kernel<<<1, 256, 0, stream>>>(pm1W, pb1W, pm2W, pb2W, kW, vW, we1W, we2W, resW, wbf);
    k1_kernel<<<2048, 256, 0, stream>>>(xyz, feat, wbf, kb, vb, pm1b, pm2b,
                                        pb1b, pb2b, we1b, we2b, val2, wgt);
    k2_kernel<<<256, 256, 0, stream>>>(wgt, mstat, rstat);
    k3_kernel<<<2048, 256, 0, stream>>>(wgt, val2, mstat, rstat, wbf, resb, (float*)d_out);
}

// Round 4
// 432.168 us; speedup vs baseline: 3.2573x; 1.1314x over previous
//
#include <hip/hip_runtime.h>
#include <hip/hip_fp16.h>

#define NKr 65536   // N*K positions per batch
#define LOG2E 1.44269504f

typedef __attribute__((ext_vector_type(4))) float f32x4;
typedef __attribute__((ext_vector_type(8))) short s16x8;

// fp32 -> bf16 (RNE)
__device__ __forceinline__ short bfc(float x){
    union{float f; unsigned u;} a; a.f = x;
    unsigned r = a.u + 0x7fffu + ((a.u >> 16) & 1u);
    return (short)(r >> 16);
}
__device__ __forceinline__ short hfc(float x){
    __half h = __float2half(x);
    return *(short*)&h;
}
__device__ __forceinline__ float hdec(unsigned short s){
    __half h = *(__half*)&s;
    return __half2float(h);
}

// ---------------------------------------------------------------------------
// K0: convert weights to bf16. wbf layout (halves): pm1p@0 [64][32] zero-pad,
// pb1p@2048, then 64x64: pm2@4096, pb2@8192, kW@12288, vW@16384, we1@20480,
// we2@24576, resW@28672.  Parallel: 64 blocks.
// ---------------------------------------------------------------------------
__global__ void k0_kernel(const float* __restrict__ pm1W, const float* __restrict__ pb1W,
                          const float* __restrict__ pm2W, const float* __restrict__ pb2W,
                          const float* __restrict__ kW,   const float* __restrict__ vW,
                          const float* __restrict__ we1W, const float* __restrict__ we2W,
                          const float* __restrict__ resW, short* __restrict__ wbf)
{
    const int tg = blockIdx.x * 256 + threadIdx.x;
    for (int i = tg; i < 32768; i += 16384){
        short v;
        if (i < 2048){
            const int o = i >> 5, c = i & 31;
            v = (c < 3) ? bfc(pm1W[o*3 + c]) : (short)0;
        } else if (i < 4096){
            const int ii = i - 2048, o = ii >> 5, c = ii & 31;
            v = (c < 3) ? bfc(pb1W[o*3 + c]) : (short)0;
        } else {
            const int m = (i - 4096) >> 12, j = (i - 4096) & 4095;
            const float* s = (m == 0) ? pm2W : (m == 1) ? pb2W : (m == 2) ? kW
                           : (m == 3) ? vW   : (m == 4) ? we1W : (m == 5) ? we2W : resW;
            v = bfc(s[j]);
        }
        wbf[i] = v;
    }
}

// ---------------------------------------------------------------------------
// MFMA helpers. Tile layout: position-major [p][64c] bf16/fp16, 128B rows,
// XOR-swizzled: half_idx = (p*64 + c) ^ ((p&7)<<3)  (16B-granule swizzle).
// MFMA mapping (16x16x32 bf16): A lane: m=li, k=hi*8+j ; B lane: k=hi*8+j,
// n=li ; D lane: row=o=16mi+4hi+j, col=p=16ni+li  (li=l&15, hi=l>>4).
// ---------------------------------------------------------------------------
__device__ __forceinline__ void gemm64(const short* __restrict__ S,
                                       const short* __restrict__ wbf, int wo,
                                       const float* __restrict__ bias,
                                       int li, int hi, f32x4 acc[4][4])
{
#pragma unroll
    for (int mi = 0; mi < 4; ++mi){
        const float4 bv = *(const float4*)(bias + 16*mi + 4*hi);
#pragma unroll
        for (int ni = 0; ni < 4; ++ni){
            acc[mi][ni][0] = bv.x; acc[mi][ni][1] = bv.y;
            acc[mi][ni][2] = bv.z; acc[mi][ni][3] = bv.w;
        }
    }
#pragma unroll
    for (int ks = 0; ks < 2; ++ks){
        s16x8 af[4];
#pragma unroll
        for (int mi = 0; mi < 4; ++mi)
            af[mi] = *(const s16x8*)(wbf + wo + (16*mi + li)*64 + ks*32 + hi*8);
#pragma unroll
        for (int ni = 0; ni < 4; ++ni){
            const int p = 16*ni + li;
            const s16x8 bf_ = *(const s16x8*)(S + ((p*64 + ks*32 + hi*8) ^ ((li & 7) << 3)));
#pragma unroll
            for (int mi = 0; mi < 4; ++mi)
                acc[mi][ni] = __builtin_amdgcn_mfma_f32_16x16x32_bf16(af[mi], bf_, acc[mi][ni], 0, 0, 0);
        }
    }
}

// K=32 GEMM with B-frags in registers (xyz, padded K 3->32)
__device__ __forceinline__ void gemm32x(const s16x8* __restrict__ xf,
                                        const short* __restrict__ wbf, int wo,
                                        const float* __restrict__ bias,
                                        int li, int hi, f32x4 acc[4][4])
{
#pragma unroll
    for (int mi = 0; mi < 4; ++mi){
        const float4 bv = *(const float4*)(bias + 16*mi + 4*hi);
#pragma unroll
        for (int ni = 0; ni < 4; ++ni){
            acc[mi][ni][0] = bv.x; acc[mi][ni][1] = bv.y;
            acc[mi][ni][2] = bv.z; acc[mi][ni][3] = bv.w;
        }
    }
    s16x8 af[4];
#pragma unroll
    for (int mi = 0; mi < 4; ++mi)
        af[mi] = *(const s16x8*)(wbf + wo + (16*mi + li)*32 + hi*8);
#pragma unroll
    for (int ni = 0; ni < 4; ++ni)
#pragma unroll
        for (int mi = 0; mi < 4; ++mi)
            acc[mi][ni] = __builtin_amdgcn_mfma_f32_16x16x32_bf16(af[mi], xf[ni], acc[mi][ni], 0, 0, 0);
}

// D-frags -> swizzled LDS tile, bf16 (optional relu)
__device__ __forceinline__ void dstore_bf(short* __restrict__ Tt, f32x4 acc[4][4],
                                          int li, int hi, bool relu)
{
#pragma unroll
    for (int mi = 0; mi < 4; ++mi){
        const int o0 = 16*mi + 4*hi;
#pragma unroll
        for (int ni = 0; ni < 4; ++ni){
            const int p = 16*ni + li;
            float a0 = acc[mi][ni][0], a1 = acc[mi][ni][1];
            float a2 = acc[mi][ni][2], a3 = acc[mi][ni][3];
            if (relu){ a0 = fmaxf(a0, 0.f); a1 = fmaxf(a1, 0.f);
                       a2 = fmaxf(a2, 0.f); a3 = fmaxf(a3, 0.f); }
            uint2 pk;
            pk.x = (unsigned)(unsigned short)bfc(a0) | ((unsigned)(unsigned short)bfc(a1) << 16);
            pk.y = (unsigned)(unsigned short)bfc(a2) | ((unsigned)(unsigned short)bfc(a3) << 16);
            *(uint2*)(Tt + ((p*64 + o0) ^ ((li & 7) << 3))) = pk;
        }
    }
}

// D-frags -> swizzled LDS tile, fp16
__device__ __forceinline__ void dstore_h16(short* __restrict__ Tt, f32x4 acc[4][4],
                                           int li, int hi)
{
#pragma unroll
    for (int mi = 0; mi < 4; ++mi){
        const int o0 = 16*mi + 4*hi;
#pragma unroll
        for (int ni = 0; ni < 4; ++ni){
            const int p = 16*ni + li;
            uint2 pk;
            pk.x = (unsigned)(unsigned short)hfc(acc[mi][ni][0]) | ((unsigned)(unsigned short)hfc(acc[mi][ni][1]) << 16);
            pk.y = (unsigned)(unsigned short)hfc(acc[mi][ni][2]) | ((unsigned)(unsigned short)hfc(acc[mi][ni][3]) << 16);
            *(uint2*)(Tt + ((p*64 + o0) ^ ((li & 7) << 3))) = pk;
        }
    }
}

// swizzled tile row l -> global (coalesced dwordx4 per 16B)
__device__ __forceinline__ void tstore(const short* __restrict__ Tt, short* __restrict__ gout, int l)
{
#pragma unroll
    for (int g = 0; g < 8; ++g){
        uint4 d = *(const uint4*)(Tt + ((l*64 + g*8) ^ ((l & 7) << 3)));
        *(uint4*)(gout + g*8) = d;
    }
}

// ---------------------------------------------------------------------------
// K1: full fused MFMA chain -> wgt (fp16, [b][r][c]) , val2 (fp16, [b][r][c])
// ONE wave per block, 16KB LDS -> 10 blocks/CU (was 2).  Zero barriers.
// ---------------------------------------------------------------------------
__global__ void __launch_bounds__(64) k1_kernel(
    const float* __restrict__ xyz, const float* __restrict__ feat,
    const short* __restrict__ wbf,
    const float* __restrict__ kb,  const float* __restrict__ vb,
    const float* __restrict__ pm1b, const float* __restrict__ pm2b,
    const float* __restrict__ pb1b, const float* __restrict__ pb2b,
    const float* __restrict__ we1b, const float* __restrict__ we2b,
    short* __restrict__ o_val2, short* __restrict__ o_wgt)
{
    __shared__ short Fs[4096];   // 8KB feature/temp tile
    __shared__ short Ts[4096];   // 8KB temp tile
    const int l = threadIdx.x;
    const int li = l & 15, hi = l >> 4;
    short* F = Fs;
    short* T = Ts;
    const int b = blockIdx.x >> 10;
    const int rbase = (blockIdx.x & 1023) << 6;

    // ---- stage feature tile: [p=l][c] bf16, swizzled ----
    {
        const float* fb = feat + (size_t)(b * 64) * NKr + rbase + l;
#pragma unroll 4
        for (int c0 = 0; c0 < 64; c0 += 8){
            short v[8];
#pragma unroll
            for (int j = 0; j < 8; ++j) v[j] = bfc(fb[(size_t)(c0 + j) * NKr]);
            uint4 pk;
            pk.x = (unsigned)(unsigned short)v[0] | ((unsigned)(unsigned short)v[1] << 16);
            pk.y = (unsigned)(unsigned short)v[2] | ((unsigned)(unsigned short)v[3] << 16);
            pk.z = (unsigned)(unsigned short)v[4] | ((unsigned)(unsigned short)v[5] << 16);
            pk.w = (unsigned)(unsigned short)v[6] | ((unsigned)(unsigned short)v[7] << 16);
            *(uint4*)(F + ((l*64 + c0) ^ ((l & 7) << 3))) = pk;
        }
    }
    // ---- xyz B-frags in regs (K padded 3->32; only hi==0 lanes non-zero) ----
    s16x8 xf[4];
#pragma unroll
    for (int ni = 0; ni < 4; ++ni)
#pragma unroll
        for (int j = 0; j < 8; ++j) xf[ni][j] = 0;
    if (hi == 0){
        const float* xb = xyz + (size_t)(b * 3) * NKr + rbase;
#pragma unroll
        for (int ni = 0; ni < 4; ++ni){
            const int p = 16*ni + li;
            xf[ni][0] = bfc(xb[p]);
            xf[ni][1] = bfc(xb[NKr + p]);
            xf[ni][2] = bfc(xb[2*NKr + p]);
        }
    }

    f32x4 A1[4][4], A2[4][4];
    // key = kW@f + kb
    gemm64(F, wbf, 12288, kb, li, hi, A1);
    // t1 = relu(pm1@xyz + pm1b) -> T
    gemm32x(xf, wbf, 0, pm1b, li, hi, A2);
    dstore_bf(T, A2, li, hi, true);
    // pem = pm2@t1 + pm2b
    gemm64(T, wbf, 4096, pm2b, li, hi, A2);
    // kp = key * pem
#pragma unroll
    for (int mi = 0; mi < 4; ++mi)
#pragma unroll
        for (int ni = 0; ni < 4; ++ni)
#pragma unroll
            for (int j = 0; j < 4; ++j) A1[mi][ni][j] *= A2[mi][ni][j];
    // t2 = relu(pb1@xyz + pb1b) -> T
    gemm32x(xf, wbf, 2048, pb1b, li, hi, A2);
    dstore_bf(T, A2, li, hi, true);
    // peb = pb2@t2 + pb2b   (stays live in A2)
    gemm64(T, wbf, 8192, pb2b, li, hi, A2);
    // rqk = kp + peb -> T
#pragma unroll
    for (int mi = 0; mi < 4; ++mi)
#pragma unroll
        for (int ni = 0; ni < 4; ++ni)
#pragma unroll
            for (int j = 0; j < 4; ++j) A1[mi][ni][j] += A2[mi][ni][j];
    dstore_bf(T, A1, li, hi, false);
    // value = vW@f + vb ; val2 = value + peb -> F (fp16) -> global
    gemm64(F, wbf, 16384, vb, li, hi, A1);
#pragma unroll
    for (int mi = 0; mi < 4; ++mi)
#pragma unroll
        for (int ni = 0; ni < 4; ++ni)
#pragma unroll
            for (int j = 0; j < 4; ++j) A1[mi][ni][j] += A2[mi][ni][j];
    dstore_h16(F, A1, li, hi);
    const size_t rowoff = ((size_t)b * NKr + rbase + l) * 64;
    tstore(F, o_val2 + rowoff, l);
    // t3 = relu(we1@rqk + we1b) -> F
    gemm64(T, wbf, 20480, we1b, li, hi, A1);
    dstore_bf(F, A1, li, hi, true);
    // wgt = we2@t3 + we2b -> T (fp16) -> global
    gemm64(F, wbf, 24576, we2b, li, hi, A1);
    dstore_h16(T, A1, li, hi);
    tstore(T, o_wgt + rowoff, l);
}

// ---------------------------------------------------------------------------
// K2: online softmax stats over n per (b,c,k). wgt is [b][n*16+k][c] fp16.
// grid = b(8) x k(16) x chalf(2) = 256 blocks, 512 thr (8 waves/CU).
// ---------------------------------------------------------------------------
__device__ __forceinline__ void comb(float& m, float& S, float mo, float So)
{
    float mn = fmaxf(m, mo);
    S = S * exp2f((m - mn) * LOG2E) + So * exp2f((mo - mn) * LOG2E);
    m = mn;
}

__global__ void __launch_bounds__(512) k2_kernel(const short* __restrict__ wgt,
                                                 float* __restrict__ mstat,
                                                 float* __restrict__ rstat)
{
    __shared__ float redm[8][4][8], reds[8][4][8];
    const int blk = blockIdx.x;
    const int b = blk >> 5, k = (blk >> 1) & 15, h = blk & 1;
    const int t = threadIdx.x;
    const int oct = t & 3, g = t >> 2;            // c0 = h*32+oct*8 ; row group g (0..127)
    const short* wp = wgt + (size_t)b * NKr * 64 + (size_t)k * 64 + h * 32 + oct * 8;

    float m[8], S[8];
#pragma unroll
    for (int j = 0; j < 8; ++j){ m[j] = -3.0e38f; S[j] = 0.f; }
#pragma unroll 2
    for (int i = 0; i < 32; ++i){
        const int n = g + 128 * i;
        const uint4 u = *(const uint4*)(wp + (size_t)n * 1024);
        unsigned short hs[8] = {
            (unsigned short)(u.x & 0xffffu), (unsigned short)(u.x >> 16),
            (unsigned short)(u.y & 0xffffu), (unsigned short)(u.y >> 16),
            (unsigned short)(u.z & 0xffffu), (unsigned short)(u.z >> 16),
            (unsigned short)(u.w & 0xffffu), (unsigned short)(u.w >> 16)};
#pragma unroll
        for (int j = 0; j < 8; ++j){
            const float x = hdec(hs[j]);
            const float mn = fmaxf(m[j], x);
            S[j] = S[j] * exp2f((m[j] - mn) * LOG2E) + exp2f((x - mn) * LOG2E);
            m[j] = mn;
        }
    }
    // in-wave reduce across g-low (xor 4,8,16,32)
#pragma unroll
    for (int d = 4; d <= 32; d <<= 1){
#pragma unroll
        for (int j = 0; j < 8; ++j){
            float mo = __shfl_xor(m[j], d, 64);
            float So = __shfl_xor(S[j], d, 64);
            comb(m[j], S[j], mo, So);
        }
    }
    const int wv = t >> 6, ln = t & 63;
    if (ln < 4){
#pragma unroll
        for (int j = 0; j < 8; ++j){ redm[wv][ln][j] = m[j]; reds[wv][ln][j] = S[j]; }
    }
    __syncthreads();
    if (t < 32){
        const int oc = t >> 3, j = t & 7;
        float M = redm[0][oc][j], Sm = reds[0][oc][j];
#pragma unroll
        for (int wv2 = 1; wv2 < 8; ++wv2) comb(M, Sm, redm[wv2][oc][j], reds[wv2][oc][j]);
        const int idx = (b * 16 + k) * 64 + h * 32 + oc * 8 + j;
        mstat[idx] = M;
        rstat[idx] = 1.0f / Sm;
    }
}

// ---------------------------------------------------------------------------
// K3: score = exp(w-m)*rs ; feature = relu(score*val2) -> MFMA resW -> out
// ONE wave per block, 16KB LDS -> 10 blocks/CU.
// ---------------------------------------------------------------------------
__global__ void __launch_bounds__(64) k3_kernel(
    const short* __restrict__ wgt, const short* __restrict__ val2,
    const float* __restrict__ mstat, const float* __restrict__ rstat,
    const short* __restrict__ wbf, const float* __restrict__ resb,
    float* __restrict__ out)
{
    __shared__ short ftile[4096];
    __shared__ float mls[1024], rls[1024];      // [k][c] fp32, swizzled f^=((k&7)<<2)
    const int l = threadIdx.x;
    const int li = l & 15, hi = l >> 4;
    const int b = blockIdx.x >> 10;
    const int rbase = (blockIdx.x & 1023) << 6;

    {
        const float* mp = mstat + b * 1024;
        const float* rp = rstat + b * 1024;
#pragma unroll
        for (int i = 0; i < 16; ++i){
            const int f = l + 64 * i;
            const int kk = f >> 6;                 // == i
            const int fs = f ^ ((kk & 7) << 2);
            mls[fs] = mp[f];
            rls[fs] = rp[f];
        }
    }
    __syncthreads();

    short* Ft = ftile;
    const int k = l & 15;                        // rbase % 64 == 0
    const size_t rowoff = ((size_t)b * NKr + rbase + l) * 64;
    const short* wp = wgt + rowoff;
    const short* vp = val2 + rowoff;
#pragma unroll 2
    for (int g = 0; g < 8; ++g){
        const uint4 uw = *(const uint4*)(wp + g * 8);
        const uint4 uv = *(const uint4*)(vp + g * 8);
        const int f0 = (k * 64 + g * 8) ^ ((k & 7) << 2);
        const int f1 = (k * 64 + g * 8 + 4) ^ ((k & 7) << 2);
        const float4 m0 = *(const float4*)(mls + f0);
        const float4 m1 = *(const float4*)(mls + f1);
        const float4 r0 = *(const float4*)(rls + f0);
        const float4 r1 = *(const float4*)(rls + f1);
        const unsigned short ws8[8] = {
            (unsigned short)(uw.x & 0xffffu), (unsigned short)(uw.x >> 16),
            (unsigned short)(uw.y & 0xffffu), (unsigned short)(uw.y >> 16),
            (unsigned short)(uw.z & 0xffffu), (unsigned short)(uw.z >> 16),
            (unsigned short)(uw.w & 0xffffu), (unsigned short)(uw.w >> 16)};
        const unsigned short vs8[8] = {
            (unsigned short)(uv.x & 0xffffu), (unsigned short)(uv.x >> 16),
            (unsigned short)(uv.y & 0xffffu), (unsigned short)(uv.y >> 16),
            (unsigned short)(uv.z & 0xffffu), (unsigned short)(uv.z >> 16),
            (unsigned short)(uv.w & 0xffffu), (unsigned short)(uv.w >> 16)};
        const float mv[8] = {m0.x, m0.y, m0.z, m0.w, m1.x, m1.y, m1.z, m1.w};
        const float rv[8] = {r0.x, r0.y, r0.z, r0.w, r1.x, r1.y, r1.z, r1.w};
        short fo[8];
#pragma unroll
        for (int j = 0; j < 8; ++j){
            const float sc = exp2f((hdec(ws8[j]) - mv[j]) * LOG2E) * rv[j];
            fo[j] = bfc(fmaxf(sc * hdec(vs8[j]), 0.f));
        }
        uint4 pk;
        pk.x = (unsigned)(unsigned short)fo[0] | ((unsigned)(unsigned short)fo[1] << 16);
        pk.y = (unsigned)(unsigned short)fo[2] | ((unsigned)(unsigned short)fo[3] << 16);
        pk.z = (unsigned)(unsigned short)fo[4] | ((unsigned)(unsigned short)fo[5] << 16);
        pk.w = (unsigned)(unsigned short)fo[6] | ((unsigned)(unsigned short)fo[7] << 16);
        *(uint4*)(Ft + ((l * 64 + g * 8) ^ ((l & 7) << 3))) = pk;
    }
    // out = resW @ feature + resb
    f32x4 acc[4][4];
    gemm64(Ft, wbf, 28672, resb, li, hi, acc);
    float* op = out + (size_t)b * 64 * NKr;
#pragma unroll
    for (int mi = 0; mi < 4; ++mi){
        const int o0 = 16 * mi + 4 * hi;
#pragma unroll
        for (int ni = 0; ni < 4; ++ni){
            const int r = rbase + 16 * ni + li;
#pragma unroll
            for (int j = 0; j < 4; ++j)
                op[(size_t)(o0 + j) * NKr + r] = acc[mi][ni][j];
        }
    }
}

// ---------------------------------------------------------------------------
extern "C" void kernel_launch(void* const* d_in, const int* in_sizes, int n_in,
                              void* d_out, int out_size, void* d_ws, size_t ws_size,
                              hipStream_t stream)
{
    const float* xyz  = (const float*)d_in[0];
    const float* feat = (const float*)d_in[1];
    const float* kW   = (const float*)d_in[2];  const float* kb   = (const float*)d_in[3];
    const float* vW   = (const float*)d_in[4];  const float* vb   = (const float*)d_in[5];
    const float* pm1W = (const float*)d_in[6];  const float* pm1b = (const float*)d_in[7];
    const float* pm2W = (const float*)d_in[8];  const float* pm2b = (const float*)d_in[9];
    const float* pb1W = (const float*)d_in[10]; const float* pb1b = (const float*)d_in[11];
    const float* pb2W = (const float*)d_in[12]; const float* pb2b = (const float*)d_in[13];
    const float* we1W = (const float*)d_in[14]; const float* we1b = (const float*)d_in[15];
    const float* we2W = (const float*)d_in[16]; const float* we2b = (const float*)d_in[17];
    const float* resW = (const float*)d_in[18]; const float* resb = (const float*)d_in[19];

    short* wbf   = (short*)d_ws;                              // 65536 B
    float* mstat = (float*)((char*)d_ws + 65536);             // 32768 B
    float* rstat = (float*)((char*)d_ws + 98304);             // 32768 B
    short* val2  = (short*)((char*)d_ws + 131072);            // 64 MB
    short* wgt   = (short*)((char*)d_ws + 131072 + 67108864); // 64 MB

    k0_kernel<<<64, 256, 0, stream>>>(pm1W, pb1W, pm2W, pb2W, kW, vW, we1W, we2W, resW, wbf);
    k1_kernel<<<8192, 64, 0, stream>>>(xyz, feat, wbf, kb, vb, pm1b, pm2b,
                                       pb1b, pb2b, we1b, we2b, val2, wgt);
    k2_kernel<<<256, 512, 0, stream>>>(wgt, mstat, rstat);
    k3_kernel<<<8192, 64, 0, stream>>>(wgt, val2, mstat, rstat, wbf, resb, (float*)d_out);
}